// Round 4
// baseline (2467.663 us; speedup 1.0000x reference)
//
#include <hip/hip_runtime.h>

typedef __attribute__((ext_vector_type(8))) short short8;
typedef __attribute__((ext_vector_type(4))) float f32x4;
typedef __attribute__((ext_vector_type(4))) unsigned int u32x4;

#define TT 512
#define HD 1024
#define BD 64
#define NWG 256

union FRAG { u32x4 d; short8 s; };

// ---- fp32 -> bf16 round-to-nearest-even ----
__device__ __forceinline__ unsigned short f2bf(float f) {
  unsigned u = __float_as_uint(f);
  u += 0x7fffu + ((u >> 16) & 1u);
  return (unsigned short)(u >> 16);
}

// ============================================================================
// Prep: inputs [B][T][512] fp32 -> XT bf16 in MFMA A-fragment order.
// ============================================================================
__global__ void prep_xt(const float* __restrict__ x, short8* __restrict__ XT) {
  const int bid = blockIdx.x;  // b*512 + t
  const int b = bid >> 9;
  const int t = bid & 511;
  const int tid = threadIdx.x;  // k-octet
  const float* src = x + ((size_t)(b * TT + t)) * 512 + tid * 8;
  const f32x4* s4 = (const f32x4*)src;
  f32x4 lo = s4[0], hi = s4[1];
  short8 o;
#pragma unroll
  for (int j = 0; j < 4; ++j) {
    o[j] = (short)f2bf(lo[j]);
    o[4 + j] = (short)f2bf(hi[j]);
  }
  const int bt = b >> 4, m = b & 15, ks = tid >> 2, q = tid & 3;
  XT[(((size_t)bt * TT + t) * 16 + ks) * 64 + q * 16 + m] = o;
}

// u64 lines per parity buffer: [4 bt][32 ks][64 lane][4 j] = 32768
#define PARQ ((size_t)(4 * 32 * 64 * 4))

// One wide tagged read: 16x 16B coherent loads (2 tagged lines each) + wait,
// ALL inside one asm block (rule-18-safe; proven correct+stable in round 3).
#define WIDELOAD()                                                        \
  asm volatile(                                                           \
      "global_load_dwordx4 %0, %16, off sc0 sc1\n\t"                      \
      "global_load_dwordx4 %1, %16, off offset:16 sc0 sc1\n\t"            \
      "global_load_dwordx4 %2, %16, off offset:2048 sc0 sc1\n\t"          \
      "global_load_dwordx4 %3, %16, off offset:2064 sc0 sc1\n\t"          \
      "global_load_dwordx4 %4, %17, off sc0 sc1\n\t"                      \
      "global_load_dwordx4 %5, %17, off offset:16 sc0 sc1\n\t"            \
      "global_load_dwordx4 %6, %17, off offset:2048 sc0 sc1\n\t"          \
      "global_load_dwordx4 %7, %17, off offset:2064 sc0 sc1\n\t"          \
      "global_load_dwordx4 %8, %18, off sc0 sc1\n\t"                      \
      "global_load_dwordx4 %9, %18, off offset:16 sc0 sc1\n\t"            \
      "global_load_dwordx4 %10, %18, off offset:2048 sc0 sc1\n\t"         \
      "global_load_dwordx4 %11, %18, off offset:2064 sc0 sc1\n\t"         \
      "global_load_dwordx4 %12, %19, off sc0 sc1\n\t"                     \
      "global_load_dwordx4 %13, %19, off offset:16 sc0 sc1\n\t"           \
      "global_load_dwordx4 %14, %19, off offset:2048 sc0 sc1\n\t"         \
      "global_load_dwordx4 %15, %19, off offset:2064 sc0 sc1\n\t"         \
      "s_waitcnt vmcnt(0)"                                                \
      : "=&v"(A[0]), "=&v"(B[0]), "=&v"(A[1]), "=&v"(B[1]),               \
        "=&v"(A[2]), "=&v"(B[2]), "=&v"(A[3]), "=&v"(B[3]),               \
        "=&v"(A[4]), "=&v"(B[4]), "=&v"(A[5]), "=&v"(B[5]),               \
        "=&v"(A[6]), "=&v"(B[6]), "=&v"(A[7]), "=&v"(B[7])                \
      : "v"(p0), "v"(p1), "v"(p2), "v"(p3)                                \
      : "memory")

// ============================================================================
// Persistent fused GRU scan. 256 WGs = 4 groups (bt, XCD-aligned) x 64 (ct).
//
// Handoff = HINT FLAG (no ack) + ONE-SHOT TAGGED WIDE LOAD:
//   data: HF line (8B) = { h[c] bf16, h[c+1] bf16, tag u32 = step }; even-c
//         threads fire ONE tagged store, then (compiler fence, program-order
//         issue) lane0 stores flag[bt][ct][wv] = t+1. NO vmcnt ack anywhere.
//   wait: consumer wave spins on its 64 RELEVANT producer flags (1x 4B
//         coherent load/lane, load+wait+cmp+branch in ONE asm block -> cheap
//         spin, no wide-poll congestion (round-3 lesson), no rule-18 split).
//   data: hint pass -> round-3's monolithic 16-load tagged read ONCE; tags
//         == t validate (flag may outrun data in the fabric; rare miss just
//         re-runs the wide load, self-paced at LLC latency).
// Safety (proven passing in round 3; hint has no safety role): WG Y stores
// tag t+1 only after its 4 waves together validated tag t on lines from ALL
// 64 producer WGs + WG barrier => every WG finished its parity-(t-1) reads
// before that buffer is overwritten. Stale tags differ (exact match).
// LDS: wh 96KB + wx 48KB + red 16KB = 160KB exactly -> 1 WG/CU, grid=256 CUs.
// ============================================================================
__global__ __launch_bounds__(256, 1) void gru_main(
    const float* __restrict__ Wxr, const float* __restrict__ bxr,
    const float* __restrict__ Whr,
    const float* __restrict__ Wxz, const float* __restrict__ bxz,
    const float* __restrict__ Whz,
    const float* __restrict__ Wxn, const float* __restrict__ bxn,
    const float* __restrict__ Whn,
    const short8* __restrict__ XT, unsigned long long* __restrict__ HF,
    unsigned* __restrict__ flags, float* __restrict__ out) {
  extern __shared__ char lds[];
  short8* wh = (short8*)lds;             // [3][32][64]
  short8* wx = (short8*)(lds + 98304);   // [3][16][64]
  float* red = (float*)(lds + 147456);   // [4][4][64][4]

  const int wg = blockIdx.x;
  const int bt = wg & 3;   // XCD-aligned batch group
  const int ct = wg >> 2;  // 0..63 group member
  const int c0 = ct << 4;
  const int tid = threadIdx.x;
  const int wv = tid >> 6;
  const int lane = tid & 63;

  // ---- stage Wh (B-fragment order)
  for (int idx = tid; idx < 3 * 32 * 64; idx += 256) {
    const int g = idx >> 11, rem = idx & 2047, ks = rem >> 6, ln = rem & 63;
    const float* W = (g == 0) ? Whr : (g == 1) ? Whz : Whn;
    const float* src = W + (size_t)(c0 + (ln & 15)) * HD + ks * 32 + (ln >> 4) * 8;
    short8 v;
#pragma unroll
    for (int j = 0; j < 8; ++j) v[j] = (short)f2bf(src[j]);
    wh[idx] = v;
  }
  // ---- stage Wx
  for (int idx = tid; idx < 3 * 16 * 64; idx += 256) {
    const int g = idx >> 10, rem = idx & 1023, ks = rem >> 6, ln = rem & 63;
    const float* W = (g == 0) ? Wxr : (g == 1) ? Wxz : Wxn;
    const float* src = W + (size_t)(c0 + (ln & 15)) * 512 + ks * 32 + (ln >> 4) * 8;
    short8 v;
#pragma unroll
    for (int j = 0; j < 8; ++j) v[j] = (short)f2bf(src[j]);
    wx[idx] = v;
  }
  __syncthreads();

  // ---- per-thread output ownership
  const int c_off = tid & 15, b_off = tid >> 4;
  const int c = c0 + c_off;
  const int b = (bt << 4) + b_off;
  const float br_ = bxr[c], bz_ = bxz[c], bn_ = bxn[c];
  float h_old = 0.f;

  const int rl = ((b_off >> 2) << 4) + c_off;
  const int rr = b_off & 3;

  // producer tagged-line index (even-c threads store the (c,c+1) pair)
  const size_t prod_li =
      ((size_t)(bt * 32 + (c >> 5)) * 64 + ((c >> 3) & 3) * 16 + b_off) * 4 +
      ((c & 7) >> 1);
  // producer flag slot: flags[bt*256 + ct*4 + wv]
  unsigned* my_flag = flags + bt * 256 + ct * 4 + wv;
  // consumer hint: wave wv needs producers ct' in [wv*16, wv*16+16), all 4
  // waves -> flags[bt*256 + wv*64 + lane] (contiguous 256B, 1 dword/lane)
  const unsigned* hint_p = flags + bt * 256 + (wv << 6) + lane;
  // consumer byte base: this wave's 8-ks input slice, 4 lines (32B) per lane
  const char* cons_base =
      (const char*)HF + (((size_t)(bt * 32 + (wv << 3)) * 64 + lane) * 4) * 8;

  float* out_hlast = out;
  float* out_hidden = out + BD * HD;

  for (int t = 0; t < TT; ++t) {
    const int p = t & 1;
    const char* cb = cons_base + (size_t)p * (PARQ * 8);
    const char* p0 = cb;
    const char* p1 = cb + 4096;
    const char* p2 = cb + 8192;
    const char* p3 = cb + 12288;

    // ---- x fragments + x MFMAs (independent of h_t; overlaps flag flight)
    const short8* xrd = XT + (((size_t)bt * TT + t) * 16 + (wv << 2)) * 64 + lane;
    short8 xa[4];
#pragma unroll
    for (int kk = 0; kk < 4; ++kk) xa[kk] = xrd[kk * 64];

    f32x4 aR = {0.f, 0.f, 0.f, 0.f};
    f32x4 aZ = {0.f, 0.f, 0.f, 0.f};
    f32x4 aNh = {0.f, 0.f, 0.f, 0.f};
    f32x4 aNx = {0.f, 0.f, 0.f, 0.f};
#pragma unroll
    for (int kk = 0; kk < 4; ++kk) {
      const int ks = (wv << 2) + kk;
      aR = __builtin_amdgcn_mfma_f32_16x16x32_bf16(xa[kk], wx[(0 * 16 + ks) * 64 + lane], aR, 0, 0, 0);
      aZ = __builtin_amdgcn_mfma_f32_16x16x32_bf16(xa[kk], wx[(1 * 16 + ks) * 64 + lane], aZ, 0, 0, 0);
      aNx = __builtin_amdgcn_mfma_f32_16x16x32_bf16(xa[kk], wx[(2 * 16 + ks) * 64 + lane], aNx, 0, 0, 0);
    }

    // ---- hint spin: 1 coherent dword/lane; whole spin in ONE asm block
    // (stale iff flag < t; flags are monotonic per slot)
    {
      const unsigned tt_ = (unsigned)t;
      unsigned hint;
      asm volatile(
          "1:\n\t"
          "global_load_dword %0, %1, off sc0 sc1\n\t"
          "s_waitcnt vmcnt(0)\n\t"
          "v_cmp_gt_u32 vcc, %2, %0\n\t"
          "s_cbranch_vccnz 1b"
          : "=&v"(hint)
          : "v"(hint_p), "v"(tt_)
          : "vcc", "memory");
    }

    // ---- one-shot wide tagged read; tags==t validate (retry only on the
    // rare flag-outran-data race, self-paced by the load's own latency)
    u32x4 A[8], B[8];
    {
      const unsigned tt_ = (unsigned)t;
      int miss = 0;
      for (;;) {
        WIDELOAD();
        unsigned bad = 0;
#pragma unroll
        for (int kk = 0; kk < 8; ++kk) {
          bad |= (A[kk][1] ^ tt_) | (A[kk][3] ^ tt_);
          bad |= (B[kk][1] ^ tt_) | (B[kk][3] ^ tt_);
        }
        if (__all(bad == 0)) break;
        if (++miss > 4) __builtin_amdgcn_s_sleep(2);  // storm safety valve
      }
    }

    // ---- h MFMAs (fragment = data dwords of the 4 lines)
#pragma unroll
    for (int kk = 0; kk < 8; ++kk) {
      FRAG f;
      f.d = (u32x4){A[kk][0], A[kk][2], B[kk][0], B[kk][2]};
      const int ks = (wv << 3) + kk;
      aR = __builtin_amdgcn_mfma_f32_16x16x32_bf16(f.s, wh[(0 * 32 + ks) * 64 + lane], aR, 0, 0, 0);
      aZ = __builtin_amdgcn_mfma_f32_16x16x32_bf16(f.s, wh[(1 * 32 + ks) * 64 + lane], aZ, 0, 0, 0);
      aNh = __builtin_amdgcn_mfma_f32_16x16x32_bf16(f.s, wh[(2 * 32 + ks) * 64 + lane], aNh, 0, 0, 0);
    }

    // ---- single-round cross-wave K-reduction
    {
      f32x4* r4 = (f32x4*)red;
      r4[(0 * 4 + wv) * 64 + lane] = aR;
      r4[(1 * 4 + wv) * 64 + lane] = aZ;
      r4[(2 * 4 + wv) * 64 + lane] = aNh;
      r4[(3 * 4 + wv) * 64 + lane] = aNx;
    }
    __syncthreads();
    float sR = 0.f, sZ = 0.f, sNh = 0.f, sNx = 0.f;
#pragma unroll
    for (int v = 0; v < 4; ++v) {
      sR += red[((0 * 4 + v) * 64 + rl) * 4 + rr];
      sZ += red[((1 * 4 + v) * 64 + rl) * 4 + rr];
      sNh += red[((2 * 4 + v) * 64 + rl) * 4 + rr];
      sNx += red[((3 * 4 + v) * 64 + rl) * 4 + rr];
    }
    // red is rewritten next iteration; fence the buffer explicitly. Stores
    // below (tag t+1) must also come after BOTH barriers: that ordering is
    // what makes the buffer-reuse induction hold.
    __syncthreads();

    // ---- gates
    const float r = 1.f / (1.f + __expf(-(sR + br_)));
    const float z = 1.f / (1.f + __expf(-(sZ + bz_)));
    float pre_n = sNx + bn_ + r * sNh;
    pre_n = fminf(fmaxf(pre_n, -30.f), 30.f);
    const float e2 = __expf(2.f * pre_n);
    const float n = (e2 - 1.f) / (e2 + 1.f);
    const float hn = (1.f - z) * n + z * h_old;
    h_old = hn;

    // ---- tagged-line store (fire-and-forget) + un-acked hint flag
    const unsigned hb = f2bf(hn);
    const unsigned hb_hi = (unsigned)__shfl_down((int)hb, 1);

    if (t < TT - 1) {
      if (!(c_off & 1)) {
        const unsigned long long val =
            (unsigned long long)(hb | (hb_hi << 16)) |
            ((unsigned long long)(unsigned)(t + 1) << 32);
        __hip_atomic_store(HF + (size_t)((t + 1) & 1) * PARQ + prod_li, val,
                           __ATOMIC_RELAXED, __HIP_MEMORY_SCOPE_AGENT);
      }
      // compiler fence: flag must ISSUE after data stores (no ack needed;
      // arrival reorder is caught by tags)
      asm volatile("" ::: "memory");
      if (lane == 0) {
        __hip_atomic_store(my_flag, (unsigned)(t + 1), __ATOMIC_RELAXED,
                           __HIP_MEMORY_SCOPE_AGENT);
      }
      // out store drains off the critical path
      out_hidden[((size_t)b * TT + t) * HD + c] = hn;
    } else {
      out_hidden[((size_t)b * TT + t) * HD + c] = hn;
      out_hlast[(size_t)b * HD + c] = hn;
    }
  }
}

// ============================================================================
extern "C" void kernel_launch(void* const* d_in, const int* in_sizes, int n_in,
                              void* d_out, int out_size, void* d_ws, size_t ws_size,
                              hipStream_t stream) {
  const float* inputs = (const float*)d_in[0];
  const float* Wxr = (const float*)d_in[1];
  const float* bxr = (const float*)d_in[2];
  const float* Whr = (const float*)d_in[3];
  const float* Wxz = (const float*)d_in[4];
  const float* bxz = (const float*)d_in[5];
  const float* Whz = (const float*)d_in[6];
  const float* Wxn = (const float*)d_in[7];
  const float* bxn = (const float*)d_in[8];
  const float* Whn = (const float*)d_in[9];
  float* out = (float*)d_out;

  char* ws = (char*)d_ws;
  short8* XT = (short8*)ws;                                       // 33,554,432 B
  unsigned long long* HF = (unsigned long long*)(ws + 33554432);  //    524,288 B
  unsigned* flags = (unsigned*)(ws + 33554432 + 524288);          //      4,096 B

  // h0 = 0 with tag 0 (t=0 expects tag 0; hint flags 0 >= 0 pass instantly);
  // parity-1 zeroed too (tag 0 != 1 -> t=1 waits for real stores).
  hipMemsetAsync(HF, 0, 524288 + 4096, stream);
  prep_xt<<<dim3(64 * 512), dim3(64), 0, stream>>>(inputs, XT);

  (void)hipFuncSetAttribute((const void*)gru_main,
                            hipFuncAttributeMaxDynamicSharedMemorySize, 163840);
  gru_main<<<dim3(NWG), dim3(256), 163840, stream>>>(
      Wxr, bxr, Whr, Wxz, bxz, Whz, Wxn, bxn, Whn, XT, HF, flags, out);
}

// Round 5
// 1512.821 us; speedup vs baseline: 1.6312x; 1.6312x over previous
//
#include <hip/hip_runtime.h>

typedef __attribute__((ext_vector_type(8))) short short8;
typedef __attribute__((ext_vector_type(4))) float f32x4;
typedef __attribute__((ext_vector_type(4))) unsigned int u32x4;

#define TT 512
#define HD 1024
#define BD 64
#define NWG 256

union FRAG { u32x4 d; short8 s; };

// ---- fp32 -> bf16 round-to-nearest-even ----
__device__ __forceinline__ unsigned short f2bf(float f) {
  unsigned u = __float_as_uint(f);
  u += 0x7fffu + ((u >> 16) & 1u);
  return (unsigned short)(u >> 16);
}

// ============================================================================
// Prep: inputs [B][T][512] fp32 -> XT bf16 in MFMA A-fragment order.
// ============================================================================
__global__ void prep_xt(const float* __restrict__ x, short8* __restrict__ XT) {
  const int bid = blockIdx.x;  // b*512 + t
  const int b = bid >> 9;
  const int t = bid & 511;
  const int tid = threadIdx.x;  // k-octet
  const float* src = x + ((size_t)(b * TT + t)) * 512 + tid * 8;
  const f32x4* s4 = (const f32x4*)src;
  f32x4 lo = s4[0], hi = s4[1];
  short8 o;
#pragma unroll
  for (int j = 0; j < 4; ++j) {
    o[j] = (short)f2bf(lo[j]);
    o[4 + j] = (short)f2bf(hi[j]);
  }
  const int bt = b >> 4, m = b & 15, ks = tid >> 2, q = tid & 3;
  XT[(((size_t)bt * TT + t) * 16 + ks) * 64 + q * 16 + m] = o;
}

// h-state: 2 parities x [4 bt][32 ks][64 lane][8 ch bf16] = 2 x 131072 B
#define PARB ((size_t)131072)

// Per-wave wait-and-load, ONE asm block (rule-18-safe: the waits live with
// the loads; all consumed values flow out through asm outputs):
//   - spin on this wave's 64 producer-wave flags (1x 4B coherent load/lane),
//     2-deep pipelined + s_sleep de-phase -> detect quantum ~ RT/2;
//   - on pass, issue the 8x dwordx4 h loads IMMEDIATELY (no hand-back to
//     compiler-scheduled code), single vmcnt(0) drains stale flag loads
//     under the data flight.
#define WAIT_AND_LOAD()                                                   \
  asm volatile(                                                           \
      "global_load_dword %8, %10, off sc0 sc1\n\t"                        \
      "s_sleep 4\n\t"                                                     \
      "global_load_dword %9, %10, off sc0 sc1\n\t"                        \
      "1:\n\t"                                                            \
      "s_waitcnt vmcnt(1)\n\t"                                            \
      "v_cmp_gt_u32 vcc, %11, %8\n\t"                                     \
      "s_cbranch_vccz 2f\n\t"                                             \
      "global_load_dword %8, %10, off sc0 sc1\n\t"                        \
      "s_waitcnt vmcnt(1)\n\t"                                            \
      "v_cmp_gt_u32 vcc, %11, %9\n\t"                                     \
      "s_cbranch_vccz 2f\n\t"                                             \
      "global_load_dword %9, %10, off sc0 sc1\n\t"                        \
      "s_branch 1b\n\t"                                                   \
      "2:\n\t"                                                            \
      "global_load_dwordx4 %0, %12, off sc0 sc1\n\t"                      \
      "global_load_dwordx4 %1, %12, off offset:1024 sc0 sc1\n\t"          \
      "global_load_dwordx4 %2, %12, off offset:2048 sc0 sc1\n\t"          \
      "global_load_dwordx4 %3, %12, off offset:3072 sc0 sc1\n\t"          \
      "global_load_dwordx4 %4, %13, off sc0 sc1\n\t"                      \
      "global_load_dwordx4 %5, %13, off offset:1024 sc0 sc1\n\t"          \
      "global_load_dwordx4 %6, %13, off offset:2048 sc0 sc1\n\t"          \
      "global_load_dwordx4 %7, %13, off offset:3072 sc0 sc1\n\t"          \
      "s_waitcnt vmcnt(0)"                                                \
      : "=&v"(H[0]), "=&v"(H[1]), "=&v"(H[2]), "=&v"(H[3]),               \
        "=&v"(H[4]), "=&v"(H[5]), "=&v"(H[6]), "=&v"(H[7]),               \
        "=&v"(f0s), "=&v"(f1s)                                            \
      : "v"(hint_p), "v"(tt_), "v"(p0), "v"(p1)                           \
      : "vcc", "memory")

// ============================================================================
// Persistent fused GRU scan. 256 WGs = 4 groups (bt, XCD-aligned) x 64 (ct).
//
// Protocol = ROUND-0's PROVEN SCHEME (acked flag, narrow poll, exactly-once
// data read), latency-trimmed:
//   producer: paired 4B h stores (even-c threads, (c,c+1) via shfl) ->
//             s_waitcnt vmcnt(0) ack -> lane0 stores flag[bt][ct][wv]=t+1.
//   consumer: per-wave NARROWED spin on only its 16 producer WGs' 64 flags
//             (1 dword/lane), merged with the 8x16B h load in one asm block.
// Safety (== round 0): a WG's 4 waves jointly poll flags of ALL 64 producer
// WGs (wave wv covers ct' in [wv*16,(wv+1)*16)); the reduction barriers merge
// that knowledge before any h_{t+1} store -> every WG finished reading
// parity (t-1) before it is overwritten. Flag stored only after vmcnt(0)
// ack of the data stores -> flag==t certifies data visible (no races, the
// round-4 lesson). Monotonic flags, >= compare.
// LDS: wh 96KB + wx 48KB + red 16KB = 160KB exactly -> 1 WG/CU, grid=256 CUs.
// ============================================================================
__global__ __launch_bounds__(256, 1) void gru_main(
    const float* __restrict__ Wxr, const float* __restrict__ bxr,
    const float* __restrict__ Whr,
    const float* __restrict__ Wxz, const float* __restrict__ bxz,
    const float* __restrict__ Whz,
    const float* __restrict__ Wxn, const float* __restrict__ bxn,
    const float* __restrict__ Whn,
    const short8* __restrict__ XT, char* __restrict__ HFc,
    unsigned* __restrict__ flags, float* __restrict__ out) {
  extern __shared__ char lds[];
  short8* wh = (short8*)lds;             // [3][32][64]
  short8* wx = (short8*)(lds + 98304);   // [3][16][64]
  float* red = (float*)(lds + 147456);   // [4][4][64][4]

  const int wg = blockIdx.x;
  const int bt = wg & 3;   // XCD-aligned batch group
  const int ct = wg >> 2;  // 0..63 group member
  const int c0 = ct << 4;
  const int tid = threadIdx.x;
  const int wv = tid >> 6;
  const int lane = tid & 63;

  // ---- stage Wh (B-fragment order)
  for (int idx = tid; idx < 3 * 32 * 64; idx += 256) {
    const int g = idx >> 11, rem = idx & 2047, ks = rem >> 6, ln = rem & 63;
    const float* W = (g == 0) ? Whr : (g == 1) ? Whz : Whn;
    const float* src = W + (size_t)(c0 + (ln & 15)) * HD + ks * 32 + (ln >> 4) * 8;
    short8 v;
#pragma unroll
    for (int j = 0; j < 8; ++j) v[j] = (short)f2bf(src[j]);
    wh[idx] = v;
  }
  // ---- stage Wx
  for (int idx = tid; idx < 3 * 16 * 64; idx += 256) {
    const int g = idx >> 10, rem = idx & 1023, ks = rem >> 6, ln = rem & 63;
    const float* W = (g == 0) ? Wxr : (g == 1) ? Wxz : Wxn;
    const float* src = W + (size_t)(c0 + (ln & 15)) * 512 + ks * 32 + (ln >> 4) * 8;
    short8 v;
#pragma unroll
    for (int j = 0; j < 8; ++j) v[j] = (short)f2bf(src[j]);
    wx[idx] = v;
  }
  __syncthreads();

  // ---- per-thread output ownership
  const int c_off = tid & 15, b_off = tid >> 4;
  const int c = c0 + c_off;
  const int b = (bt << 4) + b_off;
  const float br_ = bxr[c], bz_ = bxz[c], bn_ = bxn[c];
  float h_old = 0.f;

  const int rl = ((b_off >> 2) << 4) + c_off;
  const int rr = b_off & 3;

  // producer h byte offset (even-c threads store the (c,c+1) dword pair)
  const size_t prod_byte =
      ((size_t)((bt * 32 + (c >> 5)) * 64 + ((c >> 3) & 3) * 16 + b_off)) * 16 +
      (size_t)(c & 7) * 2;
  // producer flag slot
  unsigned* my_flag = flags + bt * 256 + ct * 4 + wv;
  // consumer: wave wv needs producers ct' in [wv*16,(wv+1)*16), all 4 waves
  // -> 64 contiguous flag dwords, 1 per lane
  const unsigned* hint_p = flags + bt * 256 + (wv << 6) + lane;
  // consumer h base: this wave's 8-ks input slice, 16B per (ks,lane)
  const char* cons_base =
      HFc + ((size_t)(bt * 32 + (wv << 3)) * 64 + lane) * 16;

  float* out_hlast = out;
  float* out_hidden = out + BD * HD;

  for (int t = 0; t < TT; ++t) {
    const char* cb = cons_base + (size_t)(t & 1) * PARB;
    const char* p0 = cb;
    const char* p1 = cb + 4096;

    // ---- x fragments (global; hidden under step slack)
    const short8* xrd = XT + (((size_t)bt * TT + t) * 16 + (wv << 2)) * 64 + lane;
    short8 xa[4];
#pragma unroll
    for (int kk = 0; kk < 4; ++kk) xa[kk] = xrd[kk * 64];

    // ---- prefetch wh B-fragments into VGPRs (h-MFMAs fire the moment h
    // data lands; SSA values survive the asm "memory" clobber)
    short8 whf0[8], whf1[8], whf2[8];
#pragma unroll
    for (int kk = 0; kk < 8; ++kk) {
      whf0[kk] = wh[(0 * 32 + (wv << 3) + kk) * 64 + lane];
      whf1[kk] = wh[(1 * 32 + (wv << 3) + kk) * 64 + lane];
      whf2[kk] = wh[(2 * 32 + (wv << 3) + kk) * 64 + lane];
    }

    f32x4 aR = {0.f, 0.f, 0.f, 0.f};
    f32x4 aZ = {0.f, 0.f, 0.f, 0.f};
    f32x4 aNh = {0.f, 0.f, 0.f, 0.f};
    f32x4 aNx = {0.f, 0.f, 0.f, 0.f};
#pragma unroll
    for (int kk = 0; kk < 4; ++kk) {
      const int ks = (wv << 2) + kk;
      aR = __builtin_amdgcn_mfma_f32_16x16x32_bf16(xa[kk], wx[(0 * 16 + ks) * 64 + lane], aR, 0, 0, 0);
      aZ = __builtin_amdgcn_mfma_f32_16x16x32_bf16(xa[kk], wx[(1 * 16 + ks) * 64 + lane], aZ, 0, 0, 0);
      aNx = __builtin_amdgcn_mfma_f32_16x16x32_bf16(xa[kk], wx[(2 * 16 + ks) * 64 + lane], aNx, 0, 0, 0);
    }

    // ---- per-wave narrowed wait + h load (one asm block)
    u32x4 H[8];
    unsigned f0s, f1s;
    const unsigned tt_ = (unsigned)t;
    WAIT_AND_LOAD();

    // ---- h MFMAs (prefetched B-frags; A-frags straight from asm outputs)
#pragma unroll
    for (int kk = 0; kk < 8; ++kk) {
      FRAG f;
      f.d = H[kk];
      aR = __builtin_amdgcn_mfma_f32_16x16x32_bf16(f.s, whf0[kk], aR, 0, 0, 0);
      aZ = __builtin_amdgcn_mfma_f32_16x16x32_bf16(f.s, whf1[kk], aZ, 0, 0, 0);
      aNh = __builtin_amdgcn_mfma_f32_16x16x32_bf16(f.s, whf2[kk], aNh, 0, 0, 0);
    }

    // ---- single-round cross-wave K-reduction
    {
      f32x4* r4 = (f32x4*)red;
      r4[(0 * 4 + wv) * 64 + lane] = aR;
      r4[(1 * 4 + wv) * 64 + lane] = aZ;
      r4[(2 * 4 + wv) * 64 + lane] = aNh;
      r4[(3 * 4 + wv) * 64 + lane] = aNx;
    }
    __syncthreads();
    float sR = 0.f, sZ = 0.f, sNh = 0.f, sNx = 0.f;
#pragma unroll
    for (int v = 0; v < 4; ++v) {
      sR += red[((0 * 4 + v) * 64 + rl) * 4 + rr];
      sZ += red[((1 * 4 + v) * 64 + rl) * 4 + rr];
      sNh += red[((2 * 4 + v) * 64 + rl) * 4 + rr];
      sNx += red[((3 * 4 + v) * 64 + rl) * 4 + rr];
    }
    // red is rewritten next iteration; narrowed polls don't cover own-WG
    // waves, so fence the buffer explicitly (also merges the 4 waves'
    // flag knowledge -> WG-level certificate for the buffer-reuse proof).
    __syncthreads();

    // ---- gates
    const float r = 1.f / (1.f + __expf(-(sR + br_)));
    const float z = 1.f / (1.f + __expf(-(sZ + bz_)));
    float pre_n = sNx + bn_ + r * sNh;
    pre_n = fminf(fmaxf(pre_n, -30.f), 30.f);
    const float e2 = __expf(2.f * pre_n);
    const float n = (e2 - 1.f) / (e2 + 1.f);
    const float hn = (1.f - z) * n + z * h_old;
    h_old = hn;

    // ---- paired h store (4B dword), vmcnt(0) ack, then flag (R0 semantics)
    const unsigned hb = f2bf(hn);
    const unsigned hb_hi = (unsigned)__shfl_down((int)hb, 1);

    if (t < TT - 1) {
      if (!(c_off & 1)) {
        __hip_atomic_store(
            (unsigned*)(HFc + (size_t)((t + 1) & 1) * PARB + prod_byte),
            hb | (hb_hi << 16), __ATOMIC_RELAXED, __HIP_MEMORY_SCOPE_AGENT);
      }
      asm volatile("s_waitcnt vmcnt(0)" ::: "memory");  // data acked at LLC
      if (lane == 0) {
        __hip_atomic_store(my_flag, (unsigned)(t + 1), __ATOMIC_RELAXED,
                           __HIP_MEMORY_SCOPE_AGENT);
      }
      // out store drains under the next step (off the critical path)
      out_hidden[((size_t)b * TT + t) * HD + c] = hn;
    } else {
      out_hidden[((size_t)b * TT + t) * HD + c] = hn;
      out_hlast[(size_t)b * HD + c] = hn;
    }
  }
}

// ============================================================================
extern "C" void kernel_launch(void* const* d_in, const int* in_sizes, int n_in,
                              void* d_out, int out_size, void* d_ws, size_t ws_size,
                              hipStream_t stream) {
  const float* inputs = (const float*)d_in[0];
  const float* Wxr = (const float*)d_in[1];
  const float* bxr = (const float*)d_in[2];
  const float* Whr = (const float*)d_in[3];
  const float* Wxz = (const float*)d_in[4];
  const float* bxz = (const float*)d_in[5];
  const float* Whz = (const float*)d_in[6];
  const float* Wxn = (const float*)d_in[7];
  const float* bxn = (const float*)d_in[8];
  const float* Whn = (const float*)d_in[9];
  float* out = (float*)d_out;

  char* ws = (char*)d_ws;
  short8* XT = (short8*)ws;                              // 33,554,432 B
  char* HF = ws + 33554432;                              //    262,144 B
  unsigned* flags = (unsigned*)(ws + 33554432 + 262144); //      4,096 B

  // h0 = 0 (both parities) + flags = 0 (t=0 check: 0 > 0 false -> pass).
  hipMemsetAsync(HF, 0, 262144 + 4096, stream);
  prep_xt<<<dim3(64 * 512), dim3(64), 0, stream>>>(inputs, XT);

  (void)hipFuncSetAttribute((const void*)gru_main,
                            hipFuncAttributeMaxDynamicSharedMemorySize, 163840);
  gru_main<<<dim3(NWG), dim3(256), 163840, stream>>>(
      Wxr, bxr, Whr, Wxz, bxz, Whz, Wxn, bxn, Whn, XT, HF, flags, out);
}